// Round 25
// baseline (167.537 us; speedup 1.0000x reference)
//
#include <hip/hip_runtime.h>
#include <hip/hip_bf16.h>
#include <stdint.h>

typedef unsigned short u16;
typedef __attribute__((ext_vector_type(8))) short short8;
typedef __attribute__((ext_vector_type(4))) float f32x4;
typedef __attribute__((ext_vector_type(4))) u16 u16x4;

#define S_LEN 2048
#define D_DIM 1024
#define NBATCH 4
#define BM 64
#define BN 128
#define BK 32

enum { MODE_QKV = 0, MODE_SC = 2, MODE_PV = 3 };

__device__ inline u16 f2bf(float f) {
  uint32_t u = __float_as_uint(f);
  uint32_t r = (u + 0x7fffu + ((u >> 16) & 1u)) >> 16;
  return (u16)r;
}

// one kernel casts x and the 3 weight matrices into the contiguous bf16 region
// out = [xb (NBATCH*S*D) | Wq (D*D) | Wk | Wv]
__global__ __launch_bounds__(256) void cast_all(
    const float* __restrict__ x, const float* __restrict__ wq,
    const float* __restrict__ wk, const float* __restrict__ wv,
    u16* __restrict__ out) {
  const int X4 = (NBATCH * S_LEN * D_DIM) / 4;
  const int W4 = (D_DIM * D_DIM) / 4;
  const int total = X4 + 3 * W4;
  int g = blockIdx.x * blockDim.x + threadIdx.x;
  int stride = gridDim.x * blockDim.x;
  for (; g < total; g += stride) {
    const float* src;
    int si;
    if (g < X4) { src = x; si = g; }
    else if (g < X4 + W4) { src = wq; si = g - X4; }
    else if (g < X4 + 2 * W4) { src = wk; si = g - X4 - W4; }
    else { src = wv; si = g - X4 - 2 * W4; }
    f32x4 v = *reinterpret_cast<const f32x4*>(src + (long)si * 4);
    u16x4 o;
    o[0] = f2bf(v[0]); o[1] = f2bf(v[1]); o[2] = f2bf(v[2]); o[3] = f2bf(v[3]);
    *reinterpret_cast<u16x4*>(out + (long)g * 4) = o;
  }
}

// C = A (bf16 [M,K]) * B^T (bf16 [N,K]) ; lda = ldb = K.
// 64x128 tile, 4 waves as 1x4 (per-wave 64x32, acc[4][2]=32 AGPR): combined regs
// ~90 -> ~5 blocks/CU (was 3 at 128^2/acc[4][4]) = more independent barrier
// domains in the latency-bound regime (nothing saturated at R24: MFMA 30%,
// VALU 20%, LDS ~45%, HBM 16%).
// Conflict-free slot swizzle from R24 (measured 6.29M -> 0) retained.
// MODE_QKV: XCD x owns row-blocks [16x,16x+16) (2MB A-panel L2-resident).
// MODE_SC : triangular 64x128 tiles; cum(2m)=m(m+1), cum(2m+1)=(m+1)^2; 272/batch.
// MODE_PV : CU-balanced: CU group m gets br {2m,2m+1,30-2m,31-2m} = 34 work each.
template <int MODE>
__global__ __launch_bounds__(256, 2) void gemm_bt(
    const u16* __restrict__ A, const u16* __restrict__ B, void* __restrict__ C,
    int K, long strideAb, long strideBb, long strideCb, int ldc,
    float* __restrict__ aux, int nb) {
  __shared__ u16 As[2][BM * BK];   // 4 KB/buf
  __shared__ u16 Bs[2][BN * BK];   // 8 KB/buf
  __shared__ float ilds[BM];

  int br, bc, bz;
  if (MODE == MODE_SC) {
    int t;
    if (nb == NBATCH) {
      int lin = blockIdx.x;          // 0..1087
      int xcd = lin & 7;
      bz = xcd >> 1;                 // batch on XCD pair {2b,2b+1}
      t = (xcd & 1) * 136 + (lin >> 3);  // 0..271
    } else {
      bz = blockIdx.z;
      t = blockIdx.x;
    }
    // tiles before row-block r: cum(2m)=m(m+1), cum(2m+1)=(m+1)^2
    auto cum = [](int r) { int m = r >> 1; return (r & 1) ? (m + 1) * (m + 1) : m * (m + 1); };
    int r = (int)(2.0f * sqrtf((float)t + 1.0f));
    if (r > 31) r = 31;
    while (r < 31 && cum(r + 1) <= t) ++r;
    while (r > 0 && cum(r) > t) --r;
    br = r;
    bc = t - cum(r);                 // 0 .. floor(br/2)
  } else if (MODE == MODE_PV) {
    if (nb == NBATCH) {
      int lin = blockIdx.x;          // 0..1023
      int xcd = lin & 7;
      bz = xcd >> 1;
      int ch = xcd & 1;              // column half (Vt 2MB L2-resident)
      int rank = lin >> 3;           // 0..127
      int bcl = rank & 3;
      int xr = rank >> 2;            // 0..31
      int m = xr & 7, k = xr >> 3;
      // CU group m hosts br {2m, 2m+1, 30-2m, 31-2m}: work sum = 34 for all m
      br = (k == 0) ? 2 * m : (k == 1) ? 2 * m + 1 : (k == 2) ? 30 - 2 * m : 31 - 2 * m;
      bc = ch * 4 + bcl;             // 0..7 (128-col units)
    } else {
      bz = blockIdx.z;
      int xr = blockIdx.x;           // 0..31
      br = (xr & 1) ? (xr >> 1) : (31 - (xr >> 1));
      bc = blockIdx.y;               // 0..7
    }
  } else {
    // MODE_QKV: XCD-locality (confirmed lin&7 -> XCD round-robin).
    int lin = blockIdx.y * gridDim.x + blockIdx.x;  // 0..3071
    int xcd = lin & 7;
    int rank = lin >> 3;         // 0..383
    br = xcd * 16 + (rank & 15); // rows [1024*xcd, 1024*(xcd+1))
    bc = rank >> 4;              // 0..23
    bz = 0;
  }

  const u16* Ab = A + (long)bz * strideAb;
  const u16* Bb = B + (long)bz * strideBb;

  const int rowBase = br * BM;
  const int colBase = bc * BN;
  int nkt = (MODE == MODE_PV) ? 4 * ((br >> 1) + 1) : (K / BK);

  const int tid = threadIdx.x;
  const int lane = tid & 63;
  const int wc = tid >> 6;        // wave = col quarter (0..3)
  const int l15 = lane & 15;
  const int g = lane >> 4;
  const int gsw = (g ^ ((l15 >> 1) & 3)) * 8;  // swizzled read slot (u16 units)

  if (MODE == MODE_PV) {
    // inline row_inv: 4 threads/row over 32-col partial sums
    int row = tid >> 2, q4 = tid & 3;
    const float* lp = aux + (long)bz * S_LEN * 64 + (long)(rowBase + row) * 64;
    int nslot = 4 * ((br >> 1) + 1);  // slots SC wrote for this row-block
    float s = 0.f;
    for (int k = q4; k < nslot; k += 4) s += lp[k];
    s += __shfl_xor(s, 1);
    s += __shfl_xor(s, 2);
    if (q4 == 0) ilds[row] = 1.f / s;
  }

  f32x4 acc[4][2];
#pragma unroll
  for (int i = 0; i < 4; i++)
#pragma unroll
    for (int j = 0; j < 2; j++) acc[i][j] = f32x4{0.f, 0.f, 0.f, 0.f};

  const int srow = tid >> 2;                               // 0..63
  const int skc = ((tid & 3) ^ ((srow >> 1) & 3)) * 8;     // pre-swizzled src slot

  auto stage = [&](int buf, int kt) {
    const u16* ga = Ab + (long)(rowBase + srow) * K + kt * BK + skc;
    const u16* gb = Bb + (long)(colBase + srow) * K + kt * BK + skc;
    __builtin_amdgcn_global_load_lds(
        (const __attribute__((address_space(1))) void*)ga,
        (__attribute__((address_space(3))) void*)(&As[buf][tid * 8]), 16, 0, 0);
    __builtin_amdgcn_global_load_lds(
        (const __attribute__((address_space(1))) void*)gb,
        (__attribute__((address_space(3))) void*)(&Bs[buf][tid * 8]), 16, 0, 0);
    __builtin_amdgcn_global_load_lds(
        (const __attribute__((address_space(1))) void*)(gb + (long)64 * K),
        (__attribute__((address_space(3))) void*)(&Bs[buf][64 * BK + tid * 8]), 16, 0, 0);
  };

  stage(0, 0);
  __syncthreads();  // drain tile-0 loads; also covers PV's ilds write
  int cur = 0;
  for (int kt = 0; kt < nkt; ++kt) {
    if (kt + 1 < nkt) stage(cur ^ 1, kt + 1);  // prefetch in flight during compute
    short8 af[4], bf[2];
#pragma unroll
    for (int i = 0; i < 4; i++)
      af[i] = *reinterpret_cast<const short8*>(
          &As[cur][(i * 16 + l15) * BK + gsw]);
#pragma unroll
    for (int j = 0; j < 2; j++)
      bf[j] = *reinterpret_cast<const short8*>(
          &Bs[cur][(wc * 32 + j * 16 + l15) * BK + gsw]);
#pragma unroll
    for (int i = 0; i < 4; i++)
#pragma unroll
      for (int j = 0; j < 2; j++)
        acc[i][j] = __builtin_amdgcn_mfma_f32_16x16x32_bf16(af[i], bf[j], acc[i][j], 0, 0, 0);
    __syncthreads();  // vmcnt(0)+lgkmcnt(0)+barrier: next tile ready, buf reusable
    cur ^= 1;
  }

  const int lr = g * 4;
  const int lc = l15;

  if (MODE == MODE_QKV) {
    u16* Cb = (u16*)C;  // Qb base; Kb at +seg; Vt at +2*seg
    const long seg = (long)NBATCH * S_LEN * D_DIM;
    const int segi = colBase >> 10;
    const int hb = colBase & 1023;
    if (segi < 2) {
      u16* dst = Cb + (long)segi * seg;
#pragma unroll
      for (int i = 0; i < 4; i++) {
        int r0 = rowBase + i * 16 + lr;
#pragma unroll
        for (int j = 0; j < 2; j++) {
          int c0 = hb + wc * 32 + j * 16 + lc;
#pragma unroll
          for (int q = 0; q < 4; q++) dst[(long)(r0 + q) * D_DIM + c0] = f2bf(acc[i][j][q]);
        }
      }
    } else {
      u16* dst = Cb + 2 * seg;  // Vt [NBATCH][D_DIM][S_LEN]
#pragma unroll
      for (int i = 0; i < 4; i++) {
        int m0 = rowBase + i * 16 + lr;
        int b = m0 >> 11, s0 = m0 & (S_LEN - 1);
#pragma unroll
        for (int j = 0; j < 2; j++) {
          int h = hb + wc * 32 + j * 16 + lc;
          u16x4 o;
          o[0] = f2bf(acc[i][j][0]); o[1] = f2bf(acc[i][j][1]);
          o[2] = f2bf(acc[i][j][2]); o[3] = f2bf(acc[i][j][3]);
          *reinterpret_cast<u16x4*>(dst + ((long)b * D_DIM + h) * S_LEN + s0) = o;
        }
      }
    }
  } else if (MODE == MODE_SC) {
    // P' = exp(s/32 - 8), causally masked; 32-col partial sums -> aux[b][row][64]
    u16* Cb = (u16*)C + (long)bz * strideCb;
    float* lp = aux + (long)bz * S_LEN * 64;
#pragma unroll
    for (int i = 0; i < 4; i++) {
      int r0 = rowBase + i * 16 + lr;
#pragma unroll
      for (int q = 0; q < 4; q++) {
        int r = r0 + q;
        float rs = 0.f;
#pragma unroll
        for (int j = 0; j < 2; j++) {
          int c0 = colBase + wc * 32 + j * 16 + lc;
          float p = (c0 <= r) ? __expf(acc[i][j][q] * 0.03125f - 8.f) : 0.f;
          rs += p;
          Cb[(long)r * ldc + c0] = f2bf(p);
        }
#pragma unroll
        for (int off = 1; off < 16; off <<= 1) rs += __shfl_xor(rs, off);
        if ((lane & 15) == 0) lp[r * 64 + bc * 4 + wc] = rs;
      }
    }
  } else {
    float* Cb = (float*)C + (long)bz * strideCb;
#pragma unroll
    for (int i = 0; i < 4; i++) {
      int rl0 = i * 16 + lr;
#pragma unroll
      for (int j = 0; j < 2; j++) {
        int c0 = colBase + wc * 32 + j * 16 + lc;
#pragma unroll
        for (int q = 0; q < 4; q++)
          Cb[(long)(rowBase + rl0 + q) * ldc + c0] = acc[i][j][q] * ilds[rl0 + q];
      }
    }
  }
}

extern "C" void kernel_launch(void* const* d_in, const int* in_sizes, int n_in,
                              void* d_out, int out_size, void* d_ws, size_t ws_size,
                              hipStream_t stream) {
  const float* x = (const float*)d_in[0];
  const float* Wq = (const float*)d_in[1];
  const float* Wk = (const float*)d_in[2];
  const float* Wv = (const float*)d_in[3];
  float* out = (float*)d_out;

  const size_t SD = (size_t)S_LEN * D_DIM;
  const size_t SS = (size_t)S_LEN * S_LEN;
  const size_t DD = (size_t)D_DIM * D_DIM;

  size_t off = 0;
  char* ws = (char*)d_ws;
  auto alloc = [&](size_t bytes) -> char* {
    char* p = ws + off;
    off += (bytes + 255) & ~(size_t)255;
    return p;
  };
  // xb and Wqkvb contiguous so cast_all writes one region
  u16* xb = (u16*)alloc((NBATCH * SD + 3 * DD) * 2);
  u16* Wqkvb = xb + NBATCH * SD;
  u16* QKVt = (u16*)alloc(3 * NBATCH * SD * 2);   // Qb | Kb | Vt
  u16* Qb = QKVt;
  u16* Kb = QKVt + NBATCH * SD;
  u16* Vt = QKVt + 2 * NBATCH * SD;
  size_t base_off = off;
  size_t need_full = base_off + ((NBATCH * SS * 2 + 255) & ~(size_t)255) +
                     ((NBATCH * (size_t)S_LEN * 64 * 4 + 255) & ~(size_t)255);
  const int nbpar = (ws_size >= need_full) ? NBATCH : 1;
  u16* P = (u16*)alloc((size_t)nbpar * SS * 2);
  float* l_part = (float*)alloc((size_t)nbpar * S_LEN * 64 * 4);

  cast_all<<<2048, 256, 0, stream>>>(x, Wq, Wk, Wv, xb);

  // fused QKV projection: M = 8192, N = 3072, K = 1024 (64x128 tiles, 3072 blocks)
  dim3 gp((NBATCH * S_LEN) / BM, 3 * D_DIM / BN, 1);
  gemm_bt<MODE_QKV><<<gp, 256, 0, stream>>>(xb, Wqkvb, QKVt, D_DIM, 0, 0, 0, D_DIM,
                                            nullptr, NBATCH);

  if (nbpar == NBATCH) {
    // SC: 1088 = 8 XCDs x 136 tiles; PV: 1024 = 8 x 128 (batch-pair aligned)
    gemm_bt<MODE_SC><<<dim3(8 * 136, 1, 1), 256, 0, stream>>>(
        Qb, Kb, P, D_DIM, (long)SD, (long)SD, (long)SS, S_LEN, l_part, NBATCH);
    gemm_bt<MODE_PV><<<dim3(8 * 128, 1, 1), 256, 0, stream>>>(
        P, Vt, out, S_LEN, (long)SS, (long)SD, (long)SD, D_DIM, l_part, NBATCH);
  } else {
    for (int b = 0; b < NBATCH; ++b) {
      gemm_bt<MODE_SC><<<dim3(272, 1, 1), 256, 0, stream>>>(
          Qb + b * SD, Kb + b * SD, P, D_DIM, 0, 0, 0, S_LEN, l_part, 1);
      gemm_bt<MODE_PV><<<dim3(32, 8, 1), 256, 0, stream>>>(
          P, Vt + b * SD, out + b * SD, S_LEN, 0, 0, 0, D_DIM, l_part, 1);
    }
  }
}